// Round 5
// baseline (393.968 us; speedup 1.0000x reference)
//
#include <hip/hip_runtime.h>

#define Bb 4
#define Ll 2048
#define Dd 1024
#define Mm (Bb*Ll)          // 8192 rows
#define NCH 64              // scan chunks
#define CLEN (Ll/NCH)       // 32 steps per chunk

typedef __attribute__((ext_vector_type(4))) float f32x4;
typedef __attribute__((ext_vector_type(8))) short s16x8;
typedef __attribute__((ext_vector_type(4))) short s16x4;
typedef __attribute__((ext_vector_type(8))) __bf16 bf16x8;

#define WAITV4 asm volatile("s_waitcnt vmcnt(4)" ::: "memory")
#define WAITV0 asm volatile("s_waitcnt vmcnt(0)" ::: "memory")
#define BARRAW asm volatile("s_barrier" ::: "memory")

__device__ __forceinline__ float sigm(float v){ return 1.0f/(1.0f+__expf(-v)); }

__device__ __forceinline__ short bf16rne(float f){
  unsigned u = __builtin_bit_cast(unsigned, f);
  u += 0x7fffu + ((u>>16)&1u);
  return (short)(u>>16);
}
__device__ __forceinline__ float bf2f(short s){
  unsigned u = ((unsigned)(unsigned short)s) << 16;
  return __builtin_bit_cast(float, u);
}

__device__ __forceinline__ void gl_lds16(const void* g, void* l){
  __builtin_amdgcn_global_load_lds((__attribute__((address_space(1))) void*)g,
                                   (__attribute__((address_space(3))) void*)l, 16, 0, 0);
}

// C[m,n] = sum_k A[m,k] * W[n,k]  (K-contiguous both sides).
// Triple-buffered K-loop, counted vmcnt(4), raw s_barrier (1/step, no vmcnt(0) drain).
// LDS swizzle: logical kseg q of row r stored at slot q ^ ((r>>1)&3)  (16B slots, BK=32).
// MFMA via builtin -> accumulators live natively in AGPRs (no per-iter cross-file copies).
// EPI: 5=fused phase-1 (lambda-u16|phi|sigmoid by column segment)
//      3=rho-blend->bf16   4=residual out
template<int EPI>
__launch_bounds__(256)
__global__ void gemm_bt(const short* __restrict__ A0, const short* __restrict__ A1,
                        const short* __restrict__ A2, const short* __restrict__ W,
                        int K,
                        const float* __restrict__ b0, const float* __restrict__ b1,
                        const float* __restrict__ xres, const float* __restrict__ rsp,
                        const short* __restrict__ fB, const short* __restrict__ sB,
                        float* __restrict__ oF, unsigned short* __restrict__ oU,
                        short* __restrict__ oB0, short* __restrict__ oB1)
{
  __shared__ short As[3][128*32];
  __shared__ short Bs[3][128*32];
  const int tid  = threadIdx.x;
  const int lane = tid & 63;
  const int wid  = tid >> 6;
  const int wm = wid >> 1, wn = wid & 1;
  const long bn0 = (long)blockIdx.x * 128;
  const long bm0 = (long)blockIdx.y * 128;

  f32x4 acc[4][4] = {};

  const int r0 = tid >> 2;           // staging row, chunk 0 (0..63)
  const int r1 = 64 + r0;            // staging row, chunk 1
  const int j  = tid & 3;            // linear 16B slot within row
  const int sw0 = (j ^ ((r0 >> 1) & 3)) * 8;   // pre-swizzled source kseg (elems)
  const int sw1 = (j ^ ((r1 >> 1) & 3)) * 8;

  auto stage = [&](int buf, int k0){
    const short* Asrc = A0; long acol = k0;
    if (EPI == 3) {
      const int blk = k0 >> 10;
      Asrc = (blk == 0) ? A0 : ((blk == 1) ? A1 : A2);
      acol = k0 & 1023;
    }
    gl_lds16(Asrc + (bm0 + r0)*1024 + acol + sw0, &As[buf][(size_t)tid*8]);
    gl_lds16(Asrc + (bm0 + r1)*1024 + acol + sw1, &As[buf][(size_t)(256+tid)*8]);
    gl_lds16(W + (bn0 + r0)*(long)K + k0 + sw0, &Bs[buf][(size_t)tid*8]);
    gl_lds16(W + (bn0 + r1)*(long)K + k0 + sw1, &Bs[buf][(size_t)(256+tid)*8]);
  };

  auto compute = [&](int buf){
    const int q = lane >> 4;
    bf16x8 af[4], bfr[4];
    #pragma unroll
    for (int mi = 0; mi < 4; ++mi) {
      const int row = wm*64 + mi*16 + (lane & 15);
      af[mi] = __builtin_bit_cast(bf16x8,
               *(const s16x8*)&As[buf][row*32 + ((q ^ ((row>>1)&3)) << 3)]);
    }
    #pragma unroll
    for (int ni = 0; ni < 4; ++ni) {
      const int row = wn*64 + ni*16 + (lane & 15);
      bfr[ni] = __builtin_bit_cast(bf16x8,
                *(const s16x8*)&Bs[buf][row*32 + ((q ^ ((row>>1)&3)) << 3)]);
    }
    #pragma unroll
    for (int mi = 0; mi < 4; ++mi)
      #pragma unroll
      for (int ni = 0; ni < 4; ++ni)
        acc[mi][ni] = __builtin_amdgcn_mfma_f32_16x16x32_bf16(
            af[mi], bfr[ni], acc[mi][ni], 0, 0, 0);
  };

  const int NK = K >> 5;
  // prologue: tiles 0,1 staged; ensure tile 0 complete (4 outstanding = tile 1)
  stage(0, 0);
  stage(1, 32);
  WAITV4;
  BARRAW;
  // invariant at loop top: tile it resident in LDS[it%3]; tile it+1 in flight or resident.
  for (int it = 0; it < NK; ++it) {
    const bool pf = (it + 2) < NK;
    if (pf) stage((it + 2) % 3, (it + 2) << 5);
    compute(it % 3);                 // compiler inserts lgkmcnt before MFMA uses
    if (pf) { WAITV4; } else { WAITV0; }
    BARRAW;                          // all waves: tile it+1 ready; LDS[it%3] reads done
  }

  const float rs = (EPI == 4) ? rsp[0] : 0.0f;
  const int seg = (EPI == 5) ? (int)(bn0 >> 10) : 0;
  const int ecol0 = (int)bn0 + wn*64 + (lane & 15);
  const int erow0 = (int)bm0 + wm*64 + ((lane >> 4) << 2);

  #pragma unroll
  for (int mi = 0; mi < 4; ++mi) {
    #pragma unroll
    for (int ni = 0; ni < 4; ++ni) {
      const f32x4 v = acc[mi][ni];
      const int gn = ecol0 + ni*16;
      const int cn = gn & 1023;
      #pragma unroll
      for (int jj = 0; jj < 4; ++jj) {
        const long gm  = erow0 + mi*16 + jj;
        const long idx = gm*1024 + cn;
        const float val = v[jj];
        if (EPI == 5) {
          if (seg == 0) {            // lambda -> u16 fixed point (abs err 7.6e-6)
            float z = val + b0[cn];
            z = fminf(fmaxf(z, -4.0f), 4.0f);
            float l = __expf(-__expf(z));
            l = fminf(fmaxf(l, 0.001f), 0.999f);
            oU[idx] = (unsigned short)__float2uint_rn(l * 65535.0f);
          } else if (seg == 1) {     // B gate: phi = silu + 0.1 sin
            oB0[idx] = bf16rne(val*sigm(val) + 0.1f*__sinf(val));
          } else {                   // alpha
            oB1[idx] = bf16rne(sigm(val + b1[cn]));
          }
        } else if (EPI == 3) {
          const float r = sigm(val + b0[cn]);
          const float f = bf2f(fB[idx]);
          const float s = bf2f(sB[idx]);
          oB0[idx] = bf16rne(r*f + (1.0f - r)*s);
        } else {
          oF[idx] = xres[idx] + rs*val;
        }
      }
    }
  }
}

// ---------- chunked linear-recurrence scans ----------

__global__ void f_chunk1(const unsigned short* __restrict__ lmU, const short* __restrict__ bgB,
                         const float* __restrict__ fprev,
                         float* __restrict__ cP, float* __restrict__ cB)
{
  const int d = blockIdx.x*256 + threadIdx.x;
  const int c = blockIdx.y, b = blockIdx.z;
  float P = 1.0f, Bv = 0.0f;
  size_t base = ((size_t)b*Ll + (size_t)c*CLEN)*Dd + d;
  const float fp = (c == 0) ? fprev[b*Dd + d] : 0.0f;
  for (int t = 0; t < CLEN; ++t) {
    const float l = (float)lmU[base] * (1.0f/65535.0f);
    float bb = bf2f(bgB[base]);
    if (c == 0 && t == 0) bb += l*fp;   // inject f_prev into step 0
    P *= l;
    Bv = l*Bv + bb;
    base += Dd;
  }
  const size_t ci = ((size_t)b*NCH + c)*Dd + d;
  cP[ci] = P; cB[ci] = Bv;
}

__global__ void scan_carry(const float* __restrict__ cP, const float* __restrict__ cB,
                           const float* __restrict__ init,
                           float* __restrict__ H0, float* __restrict__ last_out)
{
  const int d = blockIdx.x*256 + threadIdx.x;
  const int b = blockIdx.y;
  float h = init ? init[b*Dd + d] : 0.0f;
  for (int c = 0; c < NCH; ++c) {
    const size_t ci = ((size_t)b*NCH + c)*Dd + d;
    H0[ci] = h;
    h = cP[ci]*h + cB[ci];
  }
  last_out[b*Dd + d] = h;   // state at t = L-1
}

// f replay (writes bf16 f-states) fused with s-chunk product accumulation.
__global__ void fs_mid(const unsigned short* __restrict__ lmU, const short* __restrict__ bgB,
                       const float* __restrict__ fprev, const float* __restrict__ H0f,
                       const short* __restrict__ alB,
                       short* __restrict__ fob, float* __restrict__ cPs,
                       float* __restrict__ cBs)
{
  const int d = blockIdx.x*256 + threadIdx.x;
  const int c = blockIdx.y, b = blockIdx.z;
  float h = H0f[((size_t)b*NCH + c)*Dd + d];
  float sP = 1.0f, sBv = 0.0f;
  size_t base = ((size_t)b*Ll + (size_t)c*CLEN)*Dd + d;
  const float fp = (c == 0) ? fprev[b*Dd + d] : 0.0f;
  for (int t = 0; t < CLEN; ++t) {
    const float l = (float)lmU[base] * (1.0f/65535.0f);
    float bb = bf2f(bgB[base]);
    if (c == 0 && t == 0) bb += l*fp;
    h = l*h + bb;
    const short hr = bf16rne(h);
    fob[base] = hr;
    const float fr = bf2f(hr);
    const float a = bf2f(alB[base]);
    sP *= (1.0f - a);
    sBv = (1.0f - a)*sBv + a*fr;
    base += Dd;
  }
  const size_t ci = ((size_t)b*NCH + c)*Dd + d;
  cPs[ci] = sP; cBs[ci] = sBv;
}

__global__ void s_chunk3(const short* __restrict__ alB, const short* __restrict__ fob,
                         const float* __restrict__ H0s, short* __restrict__ sob)
{
  const int d = blockIdx.x*256 + threadIdx.x;
  const int c = blockIdx.y, b = blockIdx.z;
  float h = H0s[((size_t)b*NCH + c)*Dd + d];
  size_t base = ((size_t)b*Ll + (size_t)c*CLEN)*Dd + d;
  for (int t = 0; t < CLEN; ++t) {
    const float a = bf2f(alB[base]);
    const float f = bf2f(fob[base]);
    h = h + a*(f - h);
    sob[base] = bf16rne(h);
    base += Dd;
  }
}

// one launch converts all 6 f32 sources into the contiguous bf16 region [xb|w3|wrb|opb]
__global__ void cvt6(const float* __restrict__ a0, const float* __restrict__ a1,
                     const float* __restrict__ a2, const float* __restrict__ a3,
                     const float* __restrict__ a4, const float* __restrict__ a5,
                     short* __restrict__ dst)
{
  const int n0 = (Mm*Dd)/4, n1 = (Dd*Dd)/4, n4 = (3*Dd*Dd)/4;   // vec4 counts
  const int c1 = n0, c2 = c1+n1, c3 = c2+n1, c4 = c3+n1, c5 = c4+n4, total = c5+n1;
  int i = blockIdx.x*256 + threadIdx.x;
  for (; i < total; i += gridDim.x*256) {
    const float* src; int off;
    if      (i < c1) { src = a0; off = i; }
    else if (i < c2) { src = a1; off = i - c1; }
    else if (i < c3) { src = a2; off = i - c2; }
    else if (i < c4) { src = a3; off = i - c3; }
    else if (i < c5) { src = a4; off = i - c4; }
    else             { src = a5; off = i - c5; }
    const f32x4 v = ((const f32x4*)src)[off];
    s16x4 o;
    o[0] = bf16rne(v[0]); o[1] = bf16rne(v[1]);
    o[2] = bf16rne(v[2]); o[3] = bf16rne(v[3]);
    ((s16x4*)dst)[i] = o;
  }
}

extern "C" void kernel_launch(void* const* d_in, const int* in_sizes, int n_in,
                              void* d_out, int out_size, void* d_ws, size_t ws_size,
                              hipStream_t stream)
{
  (void)in_sizes; (void)n_in; (void)out_size; (void)ws_size;
  const float* x   = (const float*)d_in[0];
  const float* fpv = (const float*)d_in[1];
  const float* spv = (const float*)d_in[2];
  const float* wl  = (const float*)d_in[3];
  const float* Pw  = (const float*)d_in[4];
  const float* Wbw = (const float*)d_in[5];
  const float* Waw = (const float*)d_in[6];
  const float* ab  = (const float*)d_in[7];
  const float* Wr  = (const float*)d_in[8];
  const float* rb  = (const float*)d_in[9];
  const float* Wo  = (const float*)d_in[10];
  const float* rs  = (const float*)d_in[11];

  float* out    = (float*)d_out;
  float* f_last = out + (size_t)Mm*Dd;
  float* s_last = f_last + (size_t)Bb*Dd;

  char* w = (char*)d_ws;
  auto alloc = [&](size_t bytes){ char* p = w; w += (bytes + 255) & ~(size_t)255; return p; };
  short* xb   = (short*)alloc((size_t)Mm*Dd*2);     // contiguous bf16 region start
  short* w3   = (short*)alloc((size_t)3*Dd*Dd*2);   // [P_lambda; W_beta; W_alpha]
  short* wrb  = (short*)alloc((size_t)Dd*3*Dd*2);
  short* opb  = (short*)alloc((size_t)Dd*Dd*2);
  unsigned short* lamU = (unsigned short*)alloc((size_t)Mm*Dd*2);
  short* bgB  = (short*)alloc((size_t)Mm*Dd*2);
  short* alB  = (short*)alloc((size_t)Mm*Dd*2);
  short* fb   = (short*)alloc((size_t)Mm*Dd*2);
  short* sb   = (short*)alloc((size_t)Mm*Dd*2);
  float* cP   = (float*)alloc((size_t)Bb*NCH*Dd*4);
  float* cB   = (float*)alloc((size_t)Bb*NCH*Dd*4);
  float* H0   = (float*)alloc((size_t)Bb*NCH*Dd*4);
  short* hm   = (short*)lamU;   // alias: lamU dead after fs_mid; rho-GEMM output

  cvt6<<<dim3(2048), dim3(256), 0, stream>>>(x, Pw, Wbw, Waw, Wr, Wo, xb);

  // fused phase-1: N=3072 (lambda | beta-phi | alpha), 24x64 = 1536 blocks
  gemm_bt<5><<<dim3(3*Dd/128, Mm/128), dim3(256), 0, stream>>>(
      xb, nullptr, nullptr, w3, Dd, wl, ab, nullptr, nullptr, nullptr, nullptr,
      nullptr, lamU, bgB, alB);

  const dim3 gs(Dd/256, NCH, Bb);
  const dim3 gc(Dd/256, Bb);
  f_chunk1<<<gs, dim3(256), 0, stream>>>(lamU, bgB, fpv, cP, cB);
  scan_carry<<<gc, dim3(256), 0, stream>>>(cP, cB, (const float*)nullptr, H0, f_last);
  fs_mid<<<gs, dim3(256), 0, stream>>>(lamU, bgB, fpv, H0, alB, fb, cP, cB);
  scan_carry<<<gc, dim3(256), 0, stream>>>(cP, cB, spv, H0, s_last);
  s_chunk3<<<gs, dim3(256), 0, stream>>>(alB, fb, H0, sb);

  // rho gate GEMM over concat(f,s,x), K=3072; blend epilogue from bf16 f/s
  gemm_bt<3><<<dim3(Dd/128, Mm/128), dim3(256), 0, stream>>>(
      fb, sb, xb, wrb, 3*Dd, rb, nullptr, nullptr, nullptr, fb, sb,
      nullptr, nullptr, hm, nullptr);

  // out projection + residual
  gemm_bt<4><<<dim3(Dd/128, Mm/128), dim3(256), 0, stream>>>(
      hm, nullptr, nullptr, opb, Dd, nullptr, nullptr, x, rs, nullptr, nullptr,
      out, nullptr, nullptr, nullptr);
}

// Round 6
// 391.520 us; speedup vs baseline: 1.0063x; 1.0063x over previous
//
#include <hip/hip_runtime.h>

#define Bb 4
#define Ll 2048
#define Dd 1024
#define Mm (Bb*Ll)          // 8192 rows
#define NCH 64              // scan chunks
#define CLEN (Ll/NCH)       // 32 steps per chunk

typedef __attribute__((ext_vector_type(4))) float f32x4;
typedef __attribute__((ext_vector_type(8))) short s16x8;
typedef __attribute__((ext_vector_type(4))) short s16x4;

#define WAITV3 asm volatile("s_waitcnt vmcnt(3)" ::: "memory")
#define WAITV0 asm volatile("s_waitcnt vmcnt(0)" ::: "memory")
#define BARRAW asm volatile("s_barrier" ::: "memory")

__device__ __forceinline__ float sigm(float v){ return 1.0f/(1.0f+__expf(-v)); }

__device__ __forceinline__ short bf16rne(float f){
  unsigned u = __builtin_bit_cast(unsigned, f);
  u += 0x7fffu + ((u>>16)&1u);
  return (short)(u>>16);
}
__device__ __forceinline__ float bf2f(short s){
  unsigned u = ((unsigned)(unsigned short)s) << 16;
  return __builtin_bit_cast(float, u);
}

__device__ __forceinline__ void gl_lds16(const void* g, void* l){
  __builtin_amdgcn_global_load_lds((__attribute__((address_space(1))) void*)g,
                                   (__attribute__((address_space(3))) void*)l, 16, 0, 0);
}

// C[m,n] = sum_k A[m,k] * W[n,k]  (K-contiguous both sides).
// BM=256 x BN=128 tile, 8 waves (4M x 2N, each wave 64x64 out), BK=32.
// Triple-buffered K-loop, counted vmcnt(3), raw s_barrier (never vmcnt(0) in steady state).
// LDS swizzle: kseg q of row r at slot q ^ ((r>>1)&3); pre-swizzled global source.
// Grid: 1-D, XCD-chunked swizzle (grid%8==0): each XCD gets contiguous by-chunks (A-panel L2 reuse).
// EPI: 5=fused phase-1 (lambda-u16|phi|sigmoid by column segment)  3=rho-blend->bf16  4=residual out
template<int EPI, int NBX>
__launch_bounds__(512)
__global__ void gemm_bt(const short* __restrict__ A0, const short* __restrict__ A1,
                        const short* __restrict__ A2, const short* __restrict__ W,
                        int K,
                        const float* __restrict__ b0, const float* __restrict__ b1,
                        const float* __restrict__ xres, const float* __restrict__ rsp,
                        const short* __restrict__ fB, const short* __restrict__ sB,
                        float* __restrict__ oF, unsigned short* __restrict__ oU,
                        short* __restrict__ oB0, short* __restrict__ oB1)
{
  __shared__ short As[3][256*32];
  __shared__ short Bs[3][128*32];
  const int tid  = threadIdx.x;
  const int lane = tid & 63;
  const int wid  = tid >> 6;
  const int wm = wid >> 1;            // 0..3  (64-row stripe of 256)
  const int wn = wid & 1;             // 0..1  (64-col stripe of 128)

  // XCD-chunked block swizzle: contiguous wgid runs per XCD -> same-by blocks share an XCD's L2
  const int cpx  = (int)gridDim.x >> 3;
  const int wgid = ((int)blockIdx.x & 7) * cpx + ((int)blockIdx.x >> 3);
  const long bn0 = (long)(wgid % NBX) * 128;
  const long bm0 = (long)(wgid / NBX) * 256;

  f32x4 acc[4][4] = {};

  const int r0 = tid >> 2;            // A rows 0..127 (call 0), B rows 0..127
  const int r1 = 128 + r0;            // A rows 128..255 (call 1)
  const int j  = tid & 3;
  const int sw = (j ^ ((r0 >> 1) & 3)) * 8;   // same for r1: (r0+128)>>1 ≡ r0>>1 (mod 4)

  auto stage = [&](int buf, int k0){
    const short* Asrc = A0; long acol = k0;
    if (EPI == 3) {
      const int blk = k0 >> 10;
      Asrc = (blk == 0) ? A0 : ((blk == 1) ? A1 : A2);
      acol = k0 & 1023;
    }
    gl_lds16(Asrc + (bm0 + r0)*1024 + acol + sw, &As[buf][(size_t)tid*8]);
    gl_lds16(Asrc + (bm0 + r1)*1024 + acol + sw, &As[buf][(size_t)(512+tid)*8]);
    gl_lds16(W + (bn0 + r0)*(long)K + k0 + sw, &Bs[buf][(size_t)tid*8]);
  };

  auto compute = [&](int buf){
    const int q = lane >> 4;
    s16x8 af[4], bfr[4];
    #pragma unroll
    for (int mi = 0; mi < 4; ++mi) {
      const int row = wm*64 + mi*16 + (lane & 15);
      af[mi] = *(const s16x8*)&As[buf][row*32 + ((q ^ ((row>>1)&3)) << 3)];
    }
    #pragma unroll
    for (int ni = 0; ni < 4; ++ni) {
      const int row = wn*64 + ni*16 + (lane & 15);
      bfr[ni] = *(const s16x8*)&Bs[buf][row*32 + ((q ^ ((row>>1)&3)) << 3)];
    }
    #pragma unroll
    for (int mi = 0; mi < 4; ++mi)
      #pragma unroll
      for (int ni = 0; ni < 4; ++ni)
        asm("v_mfma_f32_16x16x32_bf16 %0, %1, %2, %0"
            : "+v"(acc[mi][ni]) : "v"(af[mi]), "v"(bfr[ni]));
  };

  const int NK = K >> 5;
  // prologue: tiles 0,1 staged (3 loads each); vmcnt(3) -> tile 0 complete
  stage(0, 0);
  stage(1, 32);
  WAITV3;
  BARRAW;
  // invariant at loop top: tile it resident in LDS[it%3]; tile it+1 in flight or resident.
  for (int it = 0; it < NK; ++it) {
    const bool pf = (it + 2) < NK;
    if (pf) stage((it + 2) % 3, (it + 2) << 5);
    compute(it % 3);                 // compiler inserts lgkmcnt before MFMA uses
    if (pf) { WAITV3; } else { WAITV0; }
    BARRAW;                          // all waves: tile it+1 ready; LDS[it%3] reads done
  }

  const float rs = (EPI == 4) ? rsp[0] : 0.0f;
  const int seg = (EPI == 5) ? (int)(bn0 >> 10) : 0;
  const int ecol0 = (int)bn0 + wn*64 + (lane & 15);
  const int erow0 = (int)bm0 + wm*64 + ((lane >> 4) << 2);

  #pragma unroll
  for (int mi = 0; mi < 4; ++mi) {
    #pragma unroll
    for (int ni = 0; ni < 4; ++ni) {
      // MFMA->VALU read hazard fence (inline-asm MFMA: compiler can't insert nops)
      asm volatile("s_nop 7\n\ts_nop 7\n\ts_nop 7" : "+v"(acc[mi][ni]));
      const f32x4 v = acc[mi][ni];
      const int gn = ecol0 + ni*16;
      const int cn = gn & 1023;
      #pragma unroll
      for (int jj = 0; jj < 4; ++jj) {
        const long gm  = erow0 + mi*16 + jj;
        const long idx = gm*1024 + cn;
        const float val = v[jj];
        if (EPI == 5) {
          if (seg == 0) {            // lambda -> u16 fixed point (abs err 7.6e-6)
            float z = val + b0[cn];
            z = fminf(fmaxf(z, -4.0f), 4.0f);
            float l = __expf(-__expf(z));
            l = fminf(fmaxf(l, 0.001f), 0.999f);
            oU[idx] = (unsigned short)__float2uint_rn(l * 65535.0f);
          } else if (seg == 1) {     // B gate: phi = silu + 0.1 sin
            oB0[idx] = bf16rne(val*sigm(val) + 0.1f*__sinf(val));
          } else {                   // alpha
            oB1[idx] = bf16rne(sigm(val + b1[cn]));
          }
        } else if (EPI == 3) {
          const float r = sigm(val + b0[cn]);
          const float f = bf2f(fB[idx]);
          const float s = bf2f(sB[idx]);
          oB0[idx] = bf16rne(r*f + (1.0f - r)*s);
        } else {
          oF[idx] = xres[idx] + rs*val;
        }
      }
    }
  }
}

// ---------- chunked linear-recurrence scans ----------

__global__ void f_chunk1(const unsigned short* __restrict__ lmU, const short* __restrict__ bgB,
                         const float* __restrict__ fprev,
                         float* __restrict__ cP, float* __restrict__ cB)
{
  const int d = blockIdx.x*256 + threadIdx.x;
  const int c = blockIdx.y, b = blockIdx.z;
  float P = 1.0f, Bv = 0.0f;
  size_t base = ((size_t)b*Ll + (size_t)c*CLEN)*Dd + d;
  const float fp = (c == 0) ? fprev[b*Dd + d] : 0.0f;
  for (int t = 0; t < CLEN; ++t) {
    const float l = (float)lmU[base] * (1.0f/65535.0f);
    float bb = bf2f(bgB[base]);
    if (c == 0 && t == 0) bb += l*fp;   // inject f_prev into step 0
    P *= l;
    Bv = l*Bv + bb;
    base += Dd;
  }
  const size_t ci = ((size_t)b*NCH + c)*Dd + d;
  cP[ci] = P; cB[ci] = Bv;
}

__global__ void scan_carry(const float* __restrict__ cP, const float* __restrict__ cB,
                           const float* __restrict__ init,
                           float* __restrict__ H0, float* __restrict__ last_out)
{
  const int d = blockIdx.x*256 + threadIdx.x;
  const int b = blockIdx.y;
  float h = init ? init[b*Dd + d] : 0.0f;
  for (int c = 0; c < NCH; ++c) {
    const size_t ci = ((size_t)b*NCH + c)*Dd + d;
    H0[ci] = h;
    h = cP[ci]*h + cB[ci];
  }
  last_out[b*Dd + d] = h;   // state at t = L-1
}

// f replay (writes bf16 f-states) fused with s-chunk product accumulation.
__global__ void fs_mid(const unsigned short* __restrict__ lmU, const short* __restrict__ bgB,
                       const float* __restrict__ fprev, const float* __restrict__ H0f,
                       const short* __restrict__ alB,
                       short* __restrict__ fob, float* __restrict__ cPs,
                       float* __restrict__ cBs)
{
  const int d = blockIdx.x*256 + threadIdx.x;
  const int c = blockIdx.y, b = blockIdx.z;
  float h = H0f[((size_t)b*NCH + c)*Dd + d];
  float sP = 1.0f, sBv = 0.0f;
  size_t base = ((size_t)b*Ll + (size_t)c*CLEN)*Dd + d;
  const float fp = (c == 0) ? fprev[b*Dd + d] : 0.0f;
  for (int t = 0; t < CLEN; ++t) {
    const float l = (float)lmU[base] * (1.0f/65535.0f);
    float bb = bf2f(bgB[base]);
    if (c == 0 && t == 0) bb += l*fp;
    h = l*h + bb;
    const short hr = bf16rne(h);
    fob[base] = hr;
    const float fr = bf2f(hr);
    const float a = bf2f(alB[base]);
    sP *= (1.0f - a);
    sBv = (1.0f - a)*sBv + a*fr;
    base += Dd;
  }
  const size_t ci = ((size_t)b*NCH + c)*Dd + d;
  cPs[ci] = sP; cBs[ci] = sBv;
}

__global__ void s_chunk3(const short* __restrict__ alB, const short* __restrict__ fob,
                         const float* __restrict__ H0s, short* __restrict__ sob)
{
  const int d = blockIdx.x*256 + threadIdx.x;
  const int c = blockIdx.y, b = blockIdx.z;
  float h = H0s[((size_t)b*NCH + c)*Dd + d];
  size_t base = ((size_t)b*Ll + (size_t)c*CLEN)*Dd + d;
  for (int t = 0; t < CLEN; ++t) {
    const float a = bf2f(alB[base]);
    const float f = bf2f(fob[base]);
    h = h + a*(f - h);
    sob[base] = bf16rne(h);
    base += Dd;
  }
}

// one launch converts all 6 f32 sources into the contiguous bf16 region [xb|w3|wrb|opb]
__global__ void cvt6(const float* __restrict__ a0, const float* __restrict__ a1,
                     const float* __restrict__ a2, const float* __restrict__ a3,
                     const float* __restrict__ a4, const float* __restrict__ a5,
                     short* __restrict__ dst)
{
  const int n0 = (Mm*Dd)/4, n1 = (Dd*Dd)/4, n4 = (3*Dd*Dd)/4;   // vec4 counts
  const int c1 = n0, c2 = c1+n1, c3 = c2+n1, c4 = c3+n1, c5 = c4+n4, total = c5+n1;
  int i = blockIdx.x*256 + threadIdx.x;
  for (; i < total; i += gridDim.x*256) {
    const float* src; int off;
    if      (i < c1) { src = a0; off = i; }
    else if (i < c2) { src = a1; off = i - c1; }
    else if (i < c3) { src = a2; off = i - c2; }
    else if (i < c4) { src = a3; off = i - c3; }
    else if (i < c5) { src = a4; off = i - c4; }
    else             { src = a5; off = i - c5; }
    const f32x4 v = ((const f32x4*)src)[off];
    s16x4 o;
    o[0] = bf16rne(v[0]); o[1] = bf16rne(v[1]);
    o[2] = bf16rne(v[2]); o[3] = bf16rne(v[3]);
    ((s16x4*)dst)[i] = o;
  }
}

extern "C" void kernel_launch(void* const* d_in, const int* in_sizes, int n_in,
                              void* d_out, int out_size, void* d_ws, size_t ws_size,
                              hipStream_t stream)
{
  (void)in_sizes; (void)n_in; (void)out_size; (void)ws_size;
  const float* x   = (const float*)d_in[0];
  const float* fpv = (const float*)d_in[1];
  const float* spv = (const float*)d_in[2];
  const float* wl  = (const float*)d_in[3];
  const float* Pw  = (const float*)d_in[4];
  const float* Wbw = (const float*)d_in[5];
  const float* Waw = (const float*)d_in[6];
  const float* ab  = (const float*)d_in[7];
  const float* Wr  = (const float*)d_in[8];
  const float* rb  = (const float*)d_in[9];
  const float* Wo  = (const float*)d_in[10];
  const float* rs  = (const float*)d_in[11];

  float* out    = (float*)d_out;
  float* f_last = out + (size_t)Mm*Dd;
  float* s_last = f_last + (size_t)Bb*Dd;

  char* w = (char*)d_ws;
  auto alloc = [&](size_t bytes){ char* p = w; w += (bytes + 255) & ~(size_t)255; return p; };
  short* xb   = (short*)alloc((size_t)Mm*Dd*2);     // contiguous bf16 region start
  short* w3   = (short*)alloc((size_t)3*Dd*Dd*2);   // [P_lambda; W_beta; W_alpha]
  short* wrb  = (short*)alloc((size_t)Dd*3*Dd*2);
  short* opb  = (short*)alloc((size_t)Dd*Dd*2);
  unsigned short* lamU = (unsigned short*)alloc((size_t)Mm*Dd*2);
  short* bgB  = (short*)alloc((size_t)Mm*Dd*2);
  short* alB  = (short*)alloc((size_t)Mm*Dd*2);
  short* fb   = (short*)alloc((size_t)Mm*Dd*2);
  short* sb   = (short*)alloc((size_t)Mm*Dd*2);
  float* cP   = (float*)alloc((size_t)Bb*NCH*Dd*4);
  float* cB   = (float*)alloc((size_t)Bb*NCH*Dd*4);
  float* H0   = (float*)alloc((size_t)Bb*NCH*Dd*4);
  short* hm   = (short*)lamU;   // alias: lamU dead after fs_mid; rho-GEMM output

  cvt6<<<dim3(2048), dim3(256), 0, stream>>>(x, Pw, Wbw, Waw, Wr, Wo, xb);

  // fused phase-1: N=3072 (lambda | beta-phi | alpha), (8192/256)*(3072/128)=768 blocks
  gemm_bt<5, 24><<<dim3(768), dim3(512), 0, stream>>>(
      xb, nullptr, nullptr, w3, Dd, wl, ab, nullptr, nullptr, nullptr, nullptr,
      nullptr, lamU, bgB, alB);

  const dim3 gs(Dd/256, NCH, Bb);
  const dim3 gc(Dd/256, Bb);
  f_chunk1<<<gs, dim3(256), 0, stream>>>(lamU, bgB, fpv, cP, cB);
  scan_carry<<<gc, dim3(256), 0, stream>>>(cP, cB, (const float*)nullptr, H0, f_last);
  fs_mid<<<gs, dim3(256), 0, stream>>>(lamU, bgB, fpv, H0, alB, fb, cP, cB);
  scan_carry<<<gc, dim3(256), 0, stream>>>(cP, cB, spv, H0, s_last);
  s_chunk3<<<gs, dim3(256), 0, stream>>>(alB, fb, H0, sb);

  // rho gate GEMM over concat(f,s,x), K=3072; blend epilogue from bf16 f/s; 32*8=256 blocks
  gemm_bt<3, 8><<<dim3(256), dim3(512), 0, stream>>>(
      fb, sb, xb, wrb, 3*Dd, rb, nullptr, nullptr, nullptr, fb, sb,
      nullptr, nullptr, hm, nullptr);

  // out projection + residual; 256 blocks
  gemm_bt<4, 8><<<dim3(256), dim3(512), 0, stream>>>(
      hm, nullptr, nullptr, opb, Dd, nullptr, nullptr, x, rs, nullptr, nullptr,
      out, nullptr, nullptr, nullptr);
}

// Round 7
// 389.033 us; speedup vs baseline: 1.0127x; 1.0064x over previous
//
#include <hip/hip_runtime.h>

#define Bb 4
#define Ll 2048
#define Dd 1024
#define Mm (Bb*Ll)          // 8192 rows
#define NCH 64              // scan chunks
#define CLEN (Ll/NCH)       // 32 steps per chunk

typedef __attribute__((ext_vector_type(4))) float f32x4;
typedef __attribute__((ext_vector_type(8))) short s16x8;
typedef __attribute__((ext_vector_type(4))) short s16x4;

#define WAITV12 asm volatile("s_waitcnt vmcnt(12)" ::: "memory")
#define WAITV8  asm volatile("s_waitcnt vmcnt(8)"  ::: "memory")
#define WAITV4  asm volatile("s_waitcnt vmcnt(4)"  ::: "memory")
#define WAITV0  asm volatile("s_waitcnt vmcnt(0)"  ::: "memory")
#define BARRAW  asm volatile("s_barrier" ::: "memory")

__device__ __forceinline__ float sigm(float v){ return 1.0f/(1.0f+__expf(-v)); }

__device__ __forceinline__ short bf16rne(float f){
  unsigned u = __builtin_bit_cast(unsigned, f);
  u += 0x7fffu + ((u>>16)&1u);
  return (short)(u>>16);
}
__device__ __forceinline__ float bf2f(short s){
  unsigned u = ((unsigned)(unsigned short)s) << 16;
  return __builtin_bit_cast(float, u);
}

__device__ __forceinline__ void gl_lds16(const void* g, void* l){
  __builtin_amdgcn_global_load_lds((__attribute__((address_space(1))) void*)g,
                                   (__attribute__((address_space(3))) void*)l, 16, 0, 0);
}

// C[m,n] = sum_k A[m,k] * W[n,k]  (K-contiguous both sides).
// 128x128 tile, 4 waves, BK=32. FIVE LDS buffers, DEPTH-3 prefetch:
// steady state keeps 3 tiles (12 16B-loads/thread) in flight -> vmcnt(12).
// This is the MLP lever: ~48KB outstanding per block vs 24KB before.
// LDS swizzle: kseg q of row r at slot q ^ ((r>>1)&3); pre-swizzled global source.
// Grid 1-D, XCD-chunked swizzle (grid%8==0).
// EPI: 5=fused phase-1 (lambda-u16|phi|sigmoid)  3=rho-blend->bf16  4=residual out
template<int EPI, int NBX>
__launch_bounds__(256)
__global__ void gemm_bt(const short* __restrict__ A0, const short* __restrict__ A1,
                        const short* __restrict__ A2, const short* __restrict__ W,
                        int K,
                        const float* __restrict__ b0, const float* __restrict__ b1,
                        const float* __restrict__ xres, const float* __restrict__ rsp,
                        const short* __restrict__ fB, const short* __restrict__ sB,
                        float* __restrict__ oF, unsigned short* __restrict__ oU,
                        short* __restrict__ oB0, short* __restrict__ oB1)
{
  __shared__ short As[5*128*32];   // 5 x 8KB
  __shared__ short Bs[5*128*32];   // 5 x 8KB   (80KB total -> 2 blocks/CU)
  const int tid  = threadIdx.x;
  const int lane = tid & 63;
  const int wid  = tid >> 6;
  const int wm = wid >> 1, wn = wid & 1;

  const int cpx  = (int)gridDim.x >> 3;
  const int wgid = ((int)blockIdx.x & 7) * cpx + ((int)blockIdx.x >> 3);
  const long bn0 = (long)(wgid % NBX) * 128;
  const long bm0 = (long)(wgid / NBX) * 128;

  f32x4 acc[4][4] = {};

  const int r0 = tid >> 2;           // rows 0..63
  const int r1 = 64 + r0;            // rows 64..127
  const int j  = tid & 3;
  const int sw0 = (j ^ ((r0 >> 1) & 3)) * 8;
  const int sw1 = (j ^ ((r1 >> 1) & 3)) * 8;

  auto stage = [&](int buf, int k0){
    const short* Asrc = A0; long acol = k0;
    if (EPI == 3) {
      const int blk = k0 >> 10;
      Asrc = (blk == 0) ? A0 : ((blk == 1) ? A1 : A2);
      acol = k0 & 1023;
    }
    short* ab = As + buf*4096;
    short* bb = Bs + buf*4096;
    gl_lds16(Asrc + (bm0 + r0)*1024 + acol + sw0, ab + (size_t)tid*8);
    gl_lds16(Asrc + (bm0 + r1)*1024 + acol + sw1, ab + (size_t)(256+tid)*8);
    gl_lds16(W + (bn0 + r0)*(long)K + k0 + sw0, bb + (size_t)tid*8);
    gl_lds16(W + (bn0 + r1)*(long)K + k0 + sw1, bb + (size_t)(256+tid)*8);
  };

  auto compute = [&](int buf){
    const int q = lane >> 4;
    const short* ab = As + buf*4096;
    const short* bb = Bs + buf*4096;
    s16x8 af[4], bfr[4];
    #pragma unroll
    for (int mi = 0; mi < 4; ++mi) {
      const int row = wm*64 + mi*16 + (lane & 15);
      af[mi] = *(const s16x8*)&ab[row*32 + ((q ^ ((row>>1)&3)) << 3)];
    }
    #pragma unroll
    for (int ni = 0; ni < 4; ++ni) {
      const int row = wn*64 + ni*16 + (lane & 15);
      bfr[ni] = *(const s16x8*)&bb[row*32 + ((q ^ ((row>>1)&3)) << 3)];
    }
    #pragma unroll
    for (int mi = 0; mi < 4; ++mi)
      #pragma unroll
      for (int ni = 0; ni < 4; ++ni)
        asm("v_mfma_f32_16x16x32_bf16 %0, %1, %2, %0"
            : "+v"(acc[mi][ni]) : "v"(af[mi]), "v"(bfr[ni]));
  };

  const int NK = K >> 5;             // >= 32 for all our K
  // prologue: stage tiles 0..3; wait until tile 0 done (3 tiles = 12 loads out)
  stage(0, 0); stage(1, 32); stage(2, 64); stage(3, 96);
  WAITV12;
  BARRAW;
  int cur = 0, nxt = 4;              // buf of tile it, buf of tile it+4
  for (int it = 0; it < NK; ++it) {
    if (it + 4 < NK) stage(nxt, (it + 4) << 5);
    compute(cur);
    // need tile it+1 complete: outstanding-beyond = min(it+4,NK-1)-(it+1) tiles
    const int ahead = ((it + 4 < NK) ? (it + 4) : (NK - 1)) - (it + 1);
    if (ahead >= 3)      { WAITV12; }
    else if (ahead == 2) { WAITV8; }
    else if (ahead == 1) { WAITV4; }
    else                 { WAITV0; }
    BARRAW;
    if (++cur == 5) cur = 0;
    if (++nxt == 5) nxt = 0;
  }

  const float rs = (EPI == 4) ? rsp[0] : 0.0f;
  const int seg = (EPI == 5) ? (int)(bn0 >> 10) : 0;
  const int ecol0 = (int)bn0 + wn*64 + (lane & 15);
  const int erow0 = (int)bm0 + wm*64 + ((lane >> 4) << 2);

  #pragma unroll
  for (int mi = 0; mi < 4; ++mi) {
    #pragma unroll
    for (int ni = 0; ni < 4; ++ni) {
      // MFMA->VALU read hazard fence (inline-asm MFMA: compiler can't insert nops)
      asm volatile("s_nop 7\n\ts_nop 7\n\ts_nop 7" : "+v"(acc[mi][ni]));
      const f32x4 v = acc[mi][ni];
      const int gn = ecol0 + ni*16;
      const int cn = gn & 1023;
      #pragma unroll
      for (int jj = 0; jj < 4; ++jj) {
        const long gm  = erow0 + mi*16 + jj;
        const long idx = gm*1024 + cn;
        const float val = v[jj];
        if (EPI == 5) {
          if (seg == 0) {            // lambda -> u16 fixed point (abs err 7.6e-6)
            float z = val + b0[cn];
            z = fminf(fmaxf(z, -4.0f), 4.0f);
            float l = __expf(-__expf(z));
            l = fminf(fmaxf(l, 0.001f), 0.999f);
            oU[idx] = (unsigned short)__float2uint_rn(l * 65535.0f);
          } else if (seg == 1) {     // B gate: phi = silu + 0.1 sin
            oB0[idx] = bf16rne(val*sigm(val) + 0.1f*__sinf(val));
          } else {                   // alpha
            oB1[idx] = bf16rne(sigm(val + b1[cn]));
          }
        } else if (EPI == 3) {
          const float r = sigm(val + b0[cn]);
          const float f = bf2f(fB[idx]);
          const float s = bf2f(sB[idx]);
          oB0[idx] = bf16rne(r*f + (1.0f - r)*s);
        } else {
          oF[idx] = xres[idx] + rs*val;
        }
      }
    }
  }
}

// ---------- chunked linear-recurrence scans ----------

__global__ void f_chunk1(const unsigned short* __restrict__ lmU, const short* __restrict__ bgB,
                         const float* __restrict__ fprev,
                         float* __restrict__ cP, float* __restrict__ cB)
{
  const int d = blockIdx.x*256 + threadIdx.x;
  const int c = blockIdx.y, b = blockIdx.z;
  float P = 1.0f, Bv = 0.0f;
  size_t base = ((size_t)b*Ll + (size_t)c*CLEN)*Dd + d;
  const float fp = (c == 0) ? fprev[b*Dd + d] : 0.0f;
  for (int t = 0; t < CLEN; ++t) {
    const float l = (float)lmU[base] * (1.0f/65535.0f);
    float bb = bf2f(bgB[base]);
    if (c == 0 && t == 0) bb += l*fp;   // inject f_prev into step 0
    P *= l;
    Bv = l*Bv + bb;
    base += Dd;
  }
  const size_t ci = ((size_t)b*NCH + c)*Dd + d;
  cP[ci] = P; cB[ci] = Bv;
}

__global__ void scan_carry(const float* __restrict__ cP, const float* __restrict__ cB,
                           const float* __restrict__ init,
                           float* __restrict__ H0, float* __restrict__ last_out)
{
  const int d = blockIdx.x*256 + threadIdx.x;
  const int b = blockIdx.y;
  float h = init ? init[b*Dd + d] : 0.0f;
  for (int c = 0; c < NCH; ++c) {
    const size_t ci = ((size_t)b*NCH + c)*Dd + d;
    H0[ci] = h;
    h = cP[ci]*h + cB[ci];
  }
  last_out[b*Dd + d] = h;   // state at t = L-1
}

// f replay (writes bf16 f-states) fused with s-chunk product accumulation.
__global__ void fs_mid(const unsigned short* __restrict__ lmU, const short* __restrict__ bgB,
                       const float* __restrict__ fprev, const float* __restrict__ H0f,
                       const short* __restrict__ alB,
                       short* __restrict__ fob, float* __restrict__ cPs,
                       float* __restrict__ cBs)
{
  const int d = blockIdx.x*256 + threadIdx.x;
  const int c = blockIdx.y, b = blockIdx.z;
  float h = H0f[((size_t)b*NCH + c)*Dd + d];
  float sP = 1.0f, sBv = 0.0f;
  size_t base = ((size_t)b*Ll + (size_t)c*CLEN)*Dd + d;
  const float fp = (c == 0) ? fprev[b*Dd + d] : 0.0f;
  for (int t = 0; t < CLEN; ++t) {
    const float l = (float)lmU[base] * (1.0f/65535.0f);
    float bb = bf2f(bgB[base]);
    if (c == 0 && t == 0) bb += l*fp;
    h = l*h + bb;
    const short hr = bf16rne(h);
    fob[base] = hr;
    const float fr = bf2f(hr);
    const float a = bf2f(alB[base]);
    sP *= (1.0f - a);
    sBv = (1.0f - a)*sBv + a*fr;
    base += Dd;
  }
  const size_t ci = ((size_t)b*NCH + c)*Dd + d;
  cPs[ci] = sP; cBs[ci] = sBv;
}

__global__ void s_chunk3(const short* __restrict__ alB, const short* __restrict__ fob,
                         const float* __restrict__ H0s, short* __restrict__ sob)
{
  const int d = blockIdx.x*256 + threadIdx.x;
  const int c = blockIdx.y, b = blockIdx.z;
  float h = H0s[((size_t)b*NCH + c)*Dd + d];
  size_t base = ((size_t)b*Ll + (size_t)c*CLEN)*Dd + d;
  for (int t = 0; t < CLEN; ++t) {
    const float a = bf2f(alB[base]);
    const float f = bf2f(fob[base]);
    h = h + a*(f - h);
    sob[base] = bf16rne(h);
    base += Dd;
  }
}

// one launch converts all 6 f32 sources into the contiguous bf16 region [xb|w3|wrb|opb]
__global__ void cvt6(const float* __restrict__ a0, const float* __restrict__ a1,
                     const float* __restrict__ a2, const float* __restrict__ a3,
                     const float* __restrict__ a4, const float* __restrict__ a5,
                     short* __restrict__ dst)
{
  const int n0 = (Mm*Dd)/4, n1 = (Dd*Dd)/4, n4 = (3*Dd*Dd)/4;   // vec4 counts
  const int c1 = n0, c2 = c1+n1, c3 = c2+n1, c4 = c3+n1, c5 = c4+n4, total = c5+n1;
  int i = blockIdx.x*256 + threadIdx.x;
  for (; i < total; i += gridDim.x*256) {
    const float* src; int off;
    if      (i < c1) { src = a0; off = i; }
    else if (i < c2) { src = a1; off = i - c1; }
    else if (i < c3) { src = a2; off = i - c2; }
    else if (i < c4) { src = a3; off = i - c3; }
    else if (i < c5) { src = a4; off = i - c4; }
    else             { src = a5; off = i - c5; }
    const f32x4 v = ((const f32x4*)src)[off];
    s16x4 o;
    o[0] = bf16rne(v[0]); o[1] = bf16rne(v[1]);
    o[2] = bf16rne(v[2]); o[3] = bf16rne(v[3]);
    ((s16x4*)dst)[i] = o;
  }
}

extern "C" void kernel_launch(void* const* d_in, const int* in_sizes, int n_in,
                              void* d_out, int out_size, void* d_ws, size_t ws_size,
                              hipStream_t stream)
{
  (void)in_sizes; (void)n_in; (void)out_size; (void)ws_size;
  const float* x   = (const float*)d_in[0];
  const float* fpv = (const float*)d_in[1];
  const float* spv = (const float*)d_in[2];
  const float* wl  = (const float*)d_in[3];
  const float* Pw  = (const float*)d_in[4];
  const float* Wbw = (const float*)d_in[5];
  const float* Waw = (const float*)d_in[6];
  const float* ab  = (const float*)d_in[7];
  const float* Wr  = (const float*)d_in[8];
  const float* rb  = (const float*)d_in[9];
  const float* Wo  = (const float*)d_in[10];
  const float* rs  = (const float*)d_in[11];

  float* out    = (float*)d_out;
  float* f_last = out + (size_t)Mm*Dd;
  float* s_last = f_last + (size_t)Bb*Dd;

  char* w = (char*)d_ws;
  auto alloc = [&](size_t bytes){ char* p = w; w += (bytes + 255) & ~(size_t)255; return p; };
  short* xb   = (short*)alloc((size_t)Mm*Dd*2);     // contiguous bf16 region start
  short* w3   = (short*)alloc((size_t)3*Dd*Dd*2);   // [P_lambda; W_beta; W_alpha]
  short* wrb  = (short*)alloc((size_t)Dd*3*Dd*2);
  short* opb  = (short*)alloc((size_t)Dd*Dd*2);
  unsigned short* lamU = (unsigned short*)alloc((size_t)Mm*Dd*2);
  short* bgB  = (short*)alloc((size_t)Mm*Dd*2);
  short* alB  = (short*)alloc((size_t)Mm*Dd*2);
  short* fb   = (short*)alloc((size_t)Mm*Dd*2);
  short* sb   = (short*)alloc((size_t)Mm*Dd*2);
  float* cP   = (float*)alloc((size_t)Bb*NCH*Dd*4);
  float* cB   = (float*)alloc((size_t)Bb*NCH*Dd*4);
  float* H0   = (float*)alloc((size_t)Bb*NCH*Dd*4);
  short* hm   = (short*)lamU;   // alias: lamU dead after fs_mid; rho-GEMM output

  cvt6<<<dim3(2048), dim3(256), 0, stream>>>(x, Pw, Wbw, Waw, Wr, Wo, xb);

  // fused phase-1: N=3072 (lambda | beta-phi | alpha), (8192/128)*(3072/128)=1536 blocks
  gemm_bt<5, 24><<<dim3(1536), dim3(256), 0, stream>>>(
      xb, nullptr, nullptr, w3, Dd, wl, ab, nullptr, nullptr, nullptr, nullptr,
      nullptr, lamU, bgB, alB);

  const dim3 gs(Dd/256, NCH, Bb);
  const dim3 gc(Dd/256, Bb);
  f_chunk1<<<gs, dim3(256), 0, stream>>>(lamU, bgB, fpv, cP, cB);
  scan_carry<<<gc, dim3(256), 0, stream>>>(cP, cB, (const float*)nullptr, H0, f_last);
  fs_mid<<<gs, dim3(256), 0, stream>>>(lamU, bgB, fpv, H0, alB, fb, cP, cB);
  scan_carry<<<gc, dim3(256), 0, stream>>>(cP, cB, spv, H0, s_last);
  s_chunk3<<<gs, dim3(256), 0, stream>>>(alB, fb, H0, sb);

  // rho gate GEMM over concat(f,s,x), K=3072; blend epilogue from bf16 f/s; 64*8=512 blocks
  gemm_bt<3, 8><<<dim3(512), dim3(256), 0, stream>>>(
      fb, sb, xb, wrb, 3*Dd, rb, nullptr, nullptr, nullptr, fb, sb,
      nullptr, nullptr, hm, nullptr);

  // out projection + residual; 512 blocks
  gemm_bt<4, 8><<<dim3(512), dim3(256), 0, stream>>>(
      hm, nullptr, nullptr, opb, Dd, nullptr, nullptr, x, rs, nullptr, nullptr,
      out, nullptr, nullptr, nullptr);
}